// Round 8
// baseline (158.568 us; speedup 1.0000x reference)
//
#include <hip/hip_runtime.h>
#include <hip/hip_bf16.h>
#include <cmath>

#define BZ 8
#define PZ 8192
#define FZ 768
#define FI 256
#define M_TOTAL (BZ * PZ)   // 65536
#define BM 128
#define BK 32
#define NKT (FZ / BK)       // 24
#define NB_TILE (128 * BK)  // 4096 elements = 8 KB per (nb, t) B-tile

typedef __bf16 bf16_t;
typedef __bf16 bf16x8 __attribute__((ext_vector_type(8)));
typedef float f32x4 __attribute__((ext_vector_type(4)));

#define AS1 __attribute__((address_space(1)))
#define AS3 __attribute__((address_space(3)))

// ---------------- pack V_w / U_w into per-(nb,t)-tiled, pre-swizzled bf16 ----
// packed col pr = 32*j + 16*u + r  <->  orig o = 16*j + r  (u: 0=V, 1=U)
// Tile (nb = pr>>7, t): contiguous 8 KB; within it, row prl = pr&127, the
// 16B-slot `slot` (2 bits at BK=32) is stored at phys slot^((prl>>1)&3) -> a
// LINEAR DMA copy into LDS yields the conflict-free swizzled layout directly.
__global__ void pack_weights(const float* __restrict__ Vw,
                             const float* __restrict__ Uw,
                             bf16_t* __restrict__ Wc) {
    int pr = blockIdx.x;                 // 0..511
    int j = pr >> 5, u = (pr >> 4) & 1, r = pr & 15;
    const float* src = (u ? Uw : Vw) + (size_t)(j * 16 + r) * FZ;
    int nb = pr >> 7, prl = pr & 127;
    for (int k = threadIdx.x; k < FZ; k += blockDim.x) {
        int t = k >> 5, slot = (k >> 3) & 3, jj = k & 7;
        Wc[(size_t)(nb * NKT + t) * NB_TILE + prl * BK
           + ((slot ^ ((prl >> 1) & 3)) * 8 + jj)] = (bf16_t)src[k];
    }
}

// ---------------- fused GEMM + gate + w-reduce -> partial logits ----------------
// 2048 blocks x 256 threads (4 waves, 2wm x 2wn; wave tile 64x64 = 4fm x 4fn of
// 16x16x32 frags, ONE MFMA k-step per tile at BK=32). Double-buffered 2-phase
// pipeline (T3 minimum): issue stage(t+1) BEFORE compute(t); one
// vmcnt(0)+lgkm(0)+barrier per tile. 32 KB LDS + VGPR<=128 -> 4 blocks/CU.
__global__ __launch_bounds__(256, 4)
void gemm_gate(const float* __restrict__ x, const bf16_t* __restrict__ Wc,
               const float* __restrict__ Vb, const float* __restrict__ Ub,
               const float* __restrict__ ww, float* __restrict__ part) {
    __shared__ bf16_t As[2][BM * BK] __attribute__((aligned(16)));   // 2x8 KB
    __shared__ bf16_t Bs[2][128 * BK] __attribute__((aligned(16)));  // 2x8 KB

    // XCD-aware remap (R2-proven): 4 n-blocks of one m-tile share bid%8 -> same
    // XCD L2 -> x fetched from HBM ~once.
    const int bid = blockIdx.x;
    const int nb = (bid >> 3) & 3;
    const int mt = (bid & 7) | ((bid >> 5) << 3);    // 0..511
    const int tid = threadIdx.x;
    const int l = tid & 63, wv = tid >> 6;
    const int wm = wv >> 1, wn = wv & 1;             // 2M x 2N waves
    const int row0 = mt * BM;

    f32x4 acc[4][4] = {};                            // [fm][fn]
    float4 abuf[4];                                  // A(t+1): 16 fp32/thread
    const bf16_t* WcB = Wc + (size_t)nb * NKT * NB_TILE;

    // A: 4 x dwordx4 fp32 loads for tile t (rows 0..127 x 4 slots of 8 floats)
    auto issueA = [&](int t) {
        #pragma unroll
        for (int i = 0; i < 2; ++i) {
            int sidx = tid + i * 256;            // 0..511
            int row = sidx >> 2, sl = sidx & 3;
            const float* gp = x + (size_t)(row0 + row) * FZ + t * BK + sl * 8;
            abuf[2 * i]     = *(const float4*)gp;
            abuf[2 * i + 1] = *(const float4*)(gp + 4);
        }
    };
    // A: cvt bf16 + swizzled LDS write (slot^((row>>1)&3)); waits on abuf
    auto writeA = [&](int buf) {
        #pragma unroll
        for (int i = 0; i < 2; ++i) {
            int sidx = tid + i * 256;
            int row = sidx >> 2, sl = sidx & 3;
            float4 f0 = abuf[2 * i], f1 = abuf[2 * i + 1];
            bf16x8 v;
            v[0] = (bf16_t)f0.x; v[1] = (bf16_t)f0.y; v[2] = (bf16_t)f0.z; v[3] = (bf16_t)f0.w;
            v[4] = (bf16_t)f1.x; v[5] = (bf16_t)f1.y; v[6] = (bf16_t)f1.z; v[7] = (bf16_t)f1.w;
            *(bf16x8*)&As[buf][row * BK + (sl ^ ((row >> 1) & 3)) * 8] = v;
        }
    };
    // B: 2 x 1KB linear DMA per wave from pre-swizzled Wc tile
    auto issueB = [&](int t, int buf) {
        const bf16_t* src = WcB + (size_t)t * NB_TILE + wv * 1024 + l * 8;
        bf16_t* dst = &Bs[buf][wv * 1024];
        #pragma unroll
        for (int c = 0; c < 2; ++c)
            __builtin_amdgcn_global_load_lds(
                (const AS1 void*)(src + c * 512),
                (AS3 void*)(dst + c * 512), 16, 0, 0);
    };
    auto compute = [&](int buf) {
        int sg = l >> 4;                         // 16B k-slot group
        bf16x8 af[4], bfr[4];
        #pragma unroll
        for (int fm = 0; fm < 4; ++fm) {
            int row = wm * 64 + fm * 16 + (l & 15);
            af[fm] = *(const bf16x8*)&As[buf][row * BK + ((sg ^ ((row >> 1) & 3)) * 8)];
        }
        #pragma unroll
        for (int fn = 0; fn < 4; ++fn) {
            int col = wn * 64 + fn * 16 + (l & 15);
            bfr[fn] = *(const bf16x8*)&Bs[buf][col * BK + ((sg ^ ((col >> 1) & 3)) * 8)];
        }
        #pragma unroll
        for (int fm = 0; fm < 4; ++fm)
            #pragma unroll
            for (int fn = 0; fn < 4; ++fn)
                acc[fm][fn] = __builtin_amdgcn_mfma_f32_16x16x32_bf16(
                    af[fm], bfr[fn], acc[fm][fn], 0, 0, 0);
    };

    // ---- prologue: fully stage tile 0 ----
    issueB(0, 0);
    asm volatile("" ::: "memory");       // pin DMA-before-A-loads issue order
    issueA(0);
    asm volatile("" ::: "memory");
    writeA(0);                           // compiler waits vmcnt for abuf
    asm volatile("s_waitcnt vmcnt(0) lgkmcnt(0)" ::: "memory");
    __builtin_amdgcn_s_barrier();

    for (int t = 0; t < NKT; ++t) {
        const int cur = t & 1;
        if (t + 1 < NKT) {
            issueB(t + 1, cur ^ 1);      // 2 DMAs -> other buffer, fly during compute
            asm volatile("" ::: "memory");
            issueA(t + 1);               // 4 loads -> regs, fly during compute
            asm volatile("" ::: "memory");
        }
        compute(cur);
        if (t + 1 < NKT) {
            writeA(cur ^ 1);             // A(t+1) regs landed during compute
            asm volatile("s_waitcnt vmcnt(0) lgkmcnt(0)" ::: "memory");
            __builtin_amdgcn_s_barrier();
        }
    }

    // ---- epilogue: gate + reduce (HW exp: v_exp_f32) ----
    // C/D 16x16: col = l&15, row = (l>>4)*4 + e. fn pairs (2q,2q+1) hold V/U
    // logits for the SAME orig output o in the SAME lane.
    const int c16 = l & 15;
    float vb[2], ub[2], wf[2];
    #pragma unroll
    for (int q = 0; q < 2; ++q) {
        int o = (nb * 4 + wn * 2 + q) * 16 + c16;
        vb[q] = Vb[o]; ub[q] = Ub[o]; wf[q] = ww[o];
    }
    const int slot = nb * 2 + wn;                // 8 disjoint partial slots
    #pragma unroll
    for (int fm = 0; fm < 4; ++fm) {
        #pragma unroll
        for (int e = 0; e < 4; ++e) {
            float partial = 0.f;
            #pragma unroll
            for (int q = 0; q < 2; ++q) {
                float zv = acc[fm][2 * q][e] + vb[q];
                float zu = acc[fm][2 * q + 1][e] + ub[q];
                float th = 1.f - 2.f / (__expf(2.f * zv) + 1.f);   // tanh(zv)
                float sg = 1.f / (1.f + __expf(-zu));              // sigmoid(zu)
                partial += th * sg * wf[q];
            }
            partial += __shfl_xor(partial, 1);
            partial += __shfl_xor(partial, 2);
            partial += __shfl_xor(partial, 4);
            partial += __shfl_xor(partial, 8);
            if (c16 == 0) {
                int r = row0 + wm * 64 + fm * 16 + (l >> 4) * 4 + e;
                part[(size_t)slot * M_TOTAL + r] = partial;
            }
        }
    }
}

// ---------------- per-bag masked softmax ----------------
__global__ __launch_bounds__(1024)
void softmax_kernel(const float* __restrict__ part, const int* __restrict__ nonpad,
                    float* __restrict__ out) {
    __shared__ float satt[PZ];
    __shared__ float red[16];
    int b = blockIdx.x;
    int np = nonpad[b];
    int tid = threadIdx.x;

    for (int p = tid; p < PZ; p += 1024) {
        float s = 0.f;
        #pragma unroll
        for (int q = 0; q < 8; ++q) s += part[(size_t)q * M_TOTAL + b * PZ + p];
        satt[p] = s;
    }
    __syncthreads();

    float m = -3.4e38f;
    for (int p = tid; p < np; p += 1024) m = fmaxf(m, satt[p]);
    #pragma unroll
    for (int off = 32; off; off >>= 1) m = fmaxf(m, __shfl_xor(m, off));
    if ((tid & 63) == 0) red[tid >> 6] = m;
    __syncthreads();
    m = red[0];
    #pragma unroll
    for (int i = 1; i < 16; ++i) m = fmaxf(m, red[i]);
    __syncthreads();

    float sum = 0.f;
    for (int p = tid; p < np; p += 1024) sum += __expf(satt[p] - m);
    #pragma unroll
    for (int off = 32; off; off >>= 1) sum += __shfl_xor(sum, off);
    if ((tid & 63) == 0) red[tid >> 6] = sum;
    __syncthreads();
    float S = red[0];
    #pragma unroll
    for (int i = 1; i < 16; ++i) S += red[i];
    float inv = 1.f / S;

    for (int p = tid; p < PZ; p += 1024)
        out[b * PZ + p] = (p < np) ? __expf(satt[p] - m) * inv : 0.f;
}

extern "C" void kernel_launch(void* const* d_in, const int* in_sizes, int n_in,
                              void* d_out, int out_size, void* d_ws, size_t ws_size,
                              hipStream_t stream) {
    const float* x    = (const float*)d_in[0];
    const int* nonpad = (const int*)d_in[1];
    const float* V_w  = (const float*)d_in[2];
    const float* V_b  = (const float*)d_in[3];
    const float* U_w  = (const float*)d_in[4];
    const float* U_b  = (const float*)d_in[5];
    const float* w_w  = (const float*)d_in[6];
    // d_in[7] = w_b: uniform logit shift -> softmax-invariant, unused.

    bf16_t* Wc  = (bf16_t*)d_ws;                                  // 768 KB
    float* part = (float*)((char*)d_ws + (size_t)512 * FZ * 2);   // 2 MB
    float* out  = (float*)d_out;

    pack_weights<<<512, 128, 0, stream>>>(V_w, U_w, Wc);
    gemm_gate<<<2048, 256, 0, stream>>>(x, Wc, V_b, U_b, w_w, part);
    softmax_kernel<<<8, 1024, 0, stream>>>(part, nonpad, out);
}

// Round 9
// 94.033 us; speedup vs baseline: 1.6863x; 1.6863x over previous
//
#include <hip/hip_runtime.h>
#include <hip/hip_bf16.h>
#include <cmath>

#define BZ 8
#define PZ 8192
#define FZ 768
#define FI 256
#define M_TOTAL (BZ * PZ)   // 65536
#define BM 128
#define BK 64
#define NKT (FZ / BK)       // 12
#define NB_TILE (128 * BK)  // 8192 elements = 16 KB per (nb, t) B-tile

typedef __bf16 bf16_t;
typedef __bf16 bf16x8 __attribute__((ext_vector_type(8)));
typedef float f32x4 __attribute__((ext_vector_type(4)));

#define AS1 __attribute__((address_space(1)))
#define AS3 __attribute__((address_space(3)))

// ---------------- pack V_w / U_w into per-(nb,t)-tiled, pre-swizzled bf16 ----
// packed col pr = 32*j + 16*u + r  <->  orig o = 16*j + r  (u: 0=V, 1=U)
// Tile (nb = pr>>7, t): contiguous 16 KB; within it, row prl = pr&127,
// 16B-slot `slot` stored at phys slot^(prl&7)  ->  a LINEAR DMA copy into LDS
// yields the bank-conflict-free swizzled layout directly. (R6/R7-proven)
__global__ void pack_weights(const float* __restrict__ Vw,
                             const float* __restrict__ Uw,
                             bf16_t* __restrict__ Wc) {
    int pr = blockIdx.x;                 // 0..511
    int j = pr >> 5, u = (pr >> 4) & 1, r = pr & 15;
    const float* src = (u ? Uw : Vw) + (size_t)(j * 16 + r) * FZ;
    int nb = pr >> 7, prl = pr & 127;
    for (int k = threadIdx.x; k < FZ; k += blockDim.x) {
        int t = k >> 6, slot = (k >> 3) & 7, jj = k & 7;
        Wc[(size_t)(nb * NKT + t) * NB_TILE + prl * 64 + ((slot ^ (prl & 7)) * 8 + jj)]
            = (bf16_t)src[k];
    }
}

// ---------------- fused GEMM + gate + w-reduce -> partial logits ----------------
// 2048 blocks x 256 threads (4 waves, 2wm x 2wn; wave tile 64x64 = 4fm x 4fn of
// 16x16x32 frags). Distance-1 prefetch (R7-proven) with As SINGLE-buffered +
// Bs double-buffered: 48 KB LDS -> 3 blocks/CU (12 waves) while keeping one
// vmcnt(0) drain per tile. Extra barrier separates "all read As(t)" from
// "overwrite As with t+1".
__global__ __launch_bounds__(256, 3)
void gemm_gate(const float* __restrict__ x, const bf16_t* __restrict__ Wc,
               const float* __restrict__ Vb, const float* __restrict__ Ub,
               const float* __restrict__ ww, float* __restrict__ part) {
    __shared__ bf16_t As[BM * BK] __attribute__((aligned(16)));      // 16 KB
    __shared__ bf16_t Bs[2][128 * BK] __attribute__((aligned(16)));  // 2x16 KB

    // XCD-aware remap (R2-proven): 4 n-blocks of one m-tile share bid%8 -> same
    // XCD L2 -> x fetched from HBM ~once.
    const int bid = blockIdx.x;
    const int nb = (bid >> 3) & 3;
    const int mt = (bid & 7) | ((bid >> 5) << 3);    // 0..511
    const int tid = threadIdx.x;
    const int l = tid & 63, wv = tid >> 6;
    const int wm = wv >> 1, wn = wv & 1;             // 2M x 2N waves
    const int row0 = mt * BM;

    f32x4 acc[4][4] = {};                            // [fm][fn]
    float4 abuf[8];                                  // A(t+1): 32 fp32/thread
    const bf16_t* WcB = Wc + (size_t)nb * NKT * NB_TILE;

    // A: issue 8 x dwordx4 fp32 loads for tile t (rows 0..127 x 8 slots)
    auto issueA = [&](int t) {
        #pragma unroll
        for (int i = 0; i < 4; ++i) {
            int sidx = tid + i * 256;            // 0..1023
            int row = sidx >> 3, sl = sidx & 7;
            const float* gp = x + (size_t)(row0 + row) * FZ + t * BK + sl * 8;
            abuf[2 * i]     = *(const float4*)gp;
            abuf[2 * i + 1] = *(const float4*)(gp + 4);
        }
    };
    // A: cvt bf16 + swizzled LDS write (slot^(row&7)); compiler waits on abuf
    auto writeA = [&]() {
        #pragma unroll
        for (int i = 0; i < 4; ++i) {
            int sidx = tid + i * 256;
            int row = sidx >> 3, sl = sidx & 7;
            float4 f0 = abuf[2 * i], f1 = abuf[2 * i + 1];
            bf16x8 v;
            v[0] = (bf16_t)f0.x; v[1] = (bf16_t)f0.y; v[2] = (bf16_t)f0.z; v[3] = (bf16_t)f0.w;
            v[4] = (bf16_t)f1.x; v[5] = (bf16_t)f1.y; v[6] = (bf16_t)f1.z; v[7] = (bf16_t)f1.w;
            *(bf16x8*)&As[row * 64 + (sl ^ (row & 7)) * 8] = v;
        }
    };
    // B: 4 x 1KB linear DMA per wave from pre-swizzled Wc tile
    auto issueB = [&](int t, int buf) {
        const bf16_t* src = WcB + (size_t)t * NB_TILE + wv * 2048 + l * 8;
        bf16_t* dst = &Bs[buf][wv * 2048];
        #pragma unroll
        for (int c = 0; c < 4; ++c)
            __builtin_amdgcn_global_load_lds(
                (const AS1 void*)(src + c * 512),
                (AS3 void*)(dst + c * 512), 16, 0, 0);
    };
    auto compute = [&](int buf) {
        #pragma unroll
        for (int kk = 0; kk < 2; ++kk) {
            int sg = kk * 4 + (l >> 4);          // 16B k-slot group (0-conflict)
            bf16x8 af[4], bfr[4];
            #pragma unroll
            for (int fm = 0; fm < 4; ++fm) {
                int row = wm * 64 + fm * 16 + (l & 15);
                af[fm] = *(const bf16x8*)&As[row * 64 + ((sg ^ (row & 7)) * 8)];
            }
            #pragma unroll
            for (int fn = 0; fn < 4; ++fn) {
                int col = wn * 64 + fn * 16 + (l & 15);
                bfr[fn] = *(const bf16x8*)&Bs[buf][col * 64 + ((sg ^ (col & 7)) * 8)];
            }
            #pragma unroll
            for (int fm = 0; fm < 4; ++fm)
                #pragma unroll
                for (int fn = 0; fn < 4; ++fn)
                    acc[fm][fn] = __builtin_amdgcn_mfma_f32_16x16x32_bf16(
                        af[fm], bfr[fn], acc[fm][fn], 0, 0, 0);
        }
    };

    // ---- prologue: fully stage tile 0 ----
    issueB(0, 0);
    asm volatile("" ::: "memory");       // pin DMA-before-A-loads issue order
    issueA(0);
    asm volatile("" ::: "memory");
    writeA();                            // waits vmcnt for abuf automatically
    asm volatile("s_waitcnt vmcnt(0) lgkmcnt(0)" ::: "memory");
    __builtin_amdgcn_s_barrier();

    #pragma unroll
    for (int t = 0; t < NKT; ++t) {
        const int cur = t & 1;
        if (t + 1 < NKT) {
            issueB(t + 1, cur ^ 1);      // DMA -> other B buffer, flies during compute
            asm volatile("" ::: "memory");
            issueA(t + 1);               // 8 loads -> regs, fly during compute
            asm volatile("" ::: "memory");
        }
        compute(cur);
        if (t + 1 < NKT) {
            __builtin_amdgcn_s_barrier();    // all waves done reading As(t)
            writeA();                        // regs (landed during compute) -> As
            asm volatile("s_waitcnt vmcnt(0) lgkmcnt(0)" ::: "memory");
            __builtin_amdgcn_s_barrier();    // As(t+1) + Bs[cur^1](t+1) ready
        }
    }

    // ---- epilogue: gate + reduce (HW exp: v_exp_f32) ----
    // C/D 16x16: col = l&15, row = (l>>4)*4 + e. fn pairs (2q,2q+1) hold V/U
    // logits for the SAME orig output o in the SAME lane.
    const int c16 = l & 15;
    float vb[2], ub[2], wf[2];
    #pragma unroll
    for (int q = 0; q < 2; ++q) {
        int o = (nb * 4 + wn * 2 + q) * 16 + c16;
        vb[q] = Vb[o]; ub[q] = Ub[o]; wf[q] = ww[o];
    }
    const int slot = nb * 2 + wn;                // 8 disjoint partial slots
    #pragma unroll
    for (int fm = 0; fm < 4; ++fm) {
        #pragma unroll
        for (int e = 0; e < 4; ++e) {
            float partial = 0.f;
            #pragma unroll
            for (int q = 0; q < 2; ++q) {
                float zv = acc[fm][2 * q][e] + vb[q];
                float zu = acc[fm][2 * q + 1][e] + ub[q];
                float th = 1.f - 2.f / (__expf(2.f * zv) + 1.f);   // tanh(zv)
                float sg = 1.f / (1.f + __expf(-zu));              // sigmoid(zu)
                partial += th * sg * wf[q];
            }
            partial += __shfl_xor(partial, 1);
            partial += __shfl_xor(partial, 2);
            partial += __shfl_xor(partial, 4);
            partial += __shfl_xor(partial, 8);
            if (c16 == 0) {
                int r = row0 + wm * 64 + fm * 16 + (l >> 4) * 4 + e;
                part[(size_t)slot * M_TOTAL + r] = partial;
            }
        }
    }
}

// ---------------- per-bag masked softmax ----------------
__global__ __launch_bounds__(1024)
void softmax_kernel(const float* __restrict__ part, const int* __restrict__ nonpad,
                    float* __restrict__ out) {
    __shared__ float satt[PZ];
    __shared__ float red[16];
    int b = blockIdx.x;
    int np = nonpad[b];
    int tid = threadIdx.x;

    for (int p = tid; p < PZ; p += 1024) {
        float s = 0.f;
        #pragma unroll
        for (int q = 0; q < 8; ++q) s += part[(size_t)q * M_TOTAL + b * PZ + p];
        satt[p] = s;
    }
    __syncthreads();

    float m = -3.4e38f;
    for (int p = tid; p < np; p += 1024) m = fmaxf(m, satt[p]);
    #pragma unroll
    for (int off = 32; off; off >>= 1) m = fmaxf(m, __shfl_xor(m, off));
    if ((tid & 63) == 0) red[tid >> 6] = m;
    __syncthreads();
    m = red[0];
    #pragma unroll
    for (int i = 1; i < 16; ++i) m = fmaxf(m, red[i]);
    __syncthreads();

    float sum = 0.f;
    for (int p = tid; p < np; p += 1024) sum += __expf(satt[p] - m);
    #pragma unroll
    for (int off = 32; off; off >>= 1) sum += __shfl_xor(sum, off);
    if ((tid & 63) == 0) red[tid >> 6] = sum;
    __syncthreads();
    float S = red[0];
    #pragma unroll
    for (int i = 1; i < 16; ++i) S += red[i];
    float inv = 1.f / S;

    for (int p = tid; p < PZ; p += 1024)
        out[b * PZ + p] = (p < np) ? __expf(satt[p] - m) * inv : 0.f;
}

extern "C" void kernel_launch(void* const* d_in, const int* in_sizes, int n_in,
                              void* d_out, int out_size, void* d_ws, size_t ws_size,
                              hipStream_t stream) {
    const float* x    = (const float*)d_in[0];
    const int* nonpad = (const int*)d_in[1];
    const float* V_w  = (const float*)d_in[2];
    const float* V_b  = (const float*)d_in[3];
    const float* U_w  = (const float*)d_in[4];
    const float* U_b  = (const float*)d_in[5];
    const float* w_w  = (const float*)d_in[6];
    // d_in[7] = w_b: uniform logit shift -> softmax-invariant, unused.

    bf16_t* Wc  = (bf16_t*)d_ws;                                  // 768 KB
    float* part = (float*)((char*)d_ws + (size_t)512 * FZ * 2);   // 2 MB
    float* out  = (float*)d_out;

    pack_weights<<<512, 128, 0, stream>>>(V_w, U_w, Wc);
    gemm_gate<<<2048, 256, 0, stream>>>(x, Wc, V_b, U_b, w_w, part);
    softmax_kernel<<<8, 1024, 0, stream>>>(part, nonpad, out);
}